// Round 2
// baseline (846.616 us; speedup 1.0000x reference)
//
#include <hip/hip_runtime.h>
#include <hip/hip_bf16.h>

typedef __attribute__((ext_vector_type(8))) short bf16x8;   // 8 bf16 = 4 VGPRs
typedef __attribute__((ext_vector_type(4))) float f32x4;

#define WDIM 512
#define CIN 128
#define COUT 128
#define NRES 32
#define NSP 32768          // 32^3
#define NTAPS 27

// conv spatial tile: 4 x 8 x 8 = 256 outputs per block
#define TZ 4
#define TY 8
#define TXW 8
#define HVOL 600           // halo 6*10*10
#define CCH 32             // cin chunk per stage
#define NCC 4              // 128/32
#define CSTR 40            // LDS row stride in bf16 (80 B = 5*16B -> perfect 8-slot bank cover)

// ws layout (bf16x8 units of 16B from ws base):
//   [0,4096)B styles f32[8][128]
//   [4096,8192)B zeropad (zeroed in k_styles)          unit 256
//   [8192, 8192+67108864)B xt bf16 [8][32768][128]     unit 512
//   [67117056, +7077888)B wmod bf16 [8][27][128][128]
#define ZP_UNIT 256
#define XT_UNIT 512

// ---------------- kernel 1: styles + zero the pad region ----------------
__global__ void k_styles(const float* __restrict__ w,
                         const float* __restrict__ aw,
                         const float* __restrict__ ab,
                         float* __restrict__ styles,
                         float* __restrict__ zeropad) {
  int b = blockIdx.x;      // 8
  int c = threadIdx.x;     // 128
  if (b == 0) {
#pragma unroll
    for (int i = 0; i < 8; i++) zeropad[i * 128 + c] = 0.f;  // 4096 B
  }
  const float4* wr = (const float4*)(w + (size_t)b * WDIM);
  const float4* ar = (const float4*)(aw + (size_t)c * WDIM);
  float s = 0.f;
#pragma unroll 8
  for (int k = 0; k < WDIM / 4; k++) {
    float4 wv = wr[k], av = ar[k];
    s += wv.x * av.x + wv.y * av.y + wv.z * av.z + wv.w * av.w;
  }
  styles[b * CIN + c] = s * 0.04419417382415922f + ab[c];  // 1/sqrt(512)
}

// -------- kernel 2: modulate+demodulate -> bf16 wmod[b][tap][cout][cin] --------
__global__ void k_wmod(const float* __restrict__ weight,
                       const float* __restrict__ styles,
                       __hip_bfloat16* __restrict__ wmod) {
  int b = blockIdx.x >> 7;
  int co = blockIdx.x & 127;
  __shared__ float st[CIN];
  __shared__ float red[4];
  int tid = threadIdx.x;   // 256
  if (tid < CIN) st[tid] = styles[b * CIN + tid];
  __syncthreads();
  const float* wr = weight + (size_t)co * (CIN * NTAPS);  // [cin][27] for this cout
  float ss = 0.f;
  for (int o = tid; o < CIN * NTAPS; o += 256) {
    float v = wr[o] * st[o / NTAPS];
    ss += v * v;
  }
#pragma unroll
  for (int off = 32; off > 0; off >>= 1) ss += __shfl_down(ss, off);
  if ((tid & 63) == 0) red[tid >> 6] = ss;
  __syncthreads();
  float d = rsqrtf(red[0] + red[1] + red[2] + red[3] + 1e-8f);
  for (int o = tid; o < CIN * NTAPS; o += 256) {
    int t = o >> 7;
    int cin = o & 127;
    float v = wr[cin * NTAPS + t] * st[cin] * d;
    wmod[((size_t)(b * NTAPS + t) * COUT + co) * CIN + cin] = __float2bfloat16(v);
  }
}

// ---------------- kernel 2.5: x f32 [b][cin][sp] -> xt bf16 [b][sp][cin] ----------------
__global__ __launch_bounds__(256)
void k_xt(const float* __restrict__ x, __hip_bfloat16* __restrict__ xt) {
  __shared__ __align__(16) __hip_bfloat16 tile[64 * 128];  // 16 KB
  int t = threadIdx.x;
  int blk = blockIdx.x;            // 8 * 512
  int b = blk >> 9;
  int sp0 = (blk & 511) << 6;
  const float* xb = x + (size_t)b * CIN * NSP + sp0;
#pragma unroll
  for (int k = 0; k < 32; k++) {
    int idx = k * 256 + t;
    int cin = idx >> 6, spl = idx & 63;
    float v = xb[(size_t)cin * NSP + spl];
    // 16B-granular XOR swizzle so phase-2 b128 reads are conflict-free
    int byte = spl * 256 + ((cin * 2) ^ ((spl & 7) << 4));
    tile[byte >> 1] = __float2bfloat16(v);
  }
  __syncthreads();
  __hip_bfloat16* ob = xt + ((size_t)b * NSP + sp0) * CIN;
#pragma unroll
  for (int k = 0; k < 4; k++) {
    int chunk = k * 256 + t;
    int spl = chunk >> 4, slotL = chunk & 15;
    int swz = slotL ^ (spl & 7);
    bf16x8 v = *(const bf16x8*)&tile[spl * 128 + swz * 8];
    *(bf16x8*)&ob[(size_t)spl * 128 + slotL * 8] = v;
  }
}

// ---------------- kernel 3: implicit-GEMM conv + bias + lrelu*sqrt(2) ----------------
// block: 512 thr (8 waves), tile M=128(cout) x N=256(spatial), wave 64x64
__global__ __launch_bounds__(512)
void k_conv(const bf16x8* __restrict__ wsbase,      // ws as 16B units
            const __hip_bfloat16* __restrict__ wmod,
            const float* __restrict__ bias,
            float* __restrict__ out) {
  __shared__ __align__(16) __hip_bfloat16 xs[HVOL * CSTR + 8];

  static const int TOFF5[NTAPS] = {
      0,    5,    10,   50,   55,   60,   100,  105,  110,
      500,  505,  510,  550,  555,  560,  600,  605,  610,
      1000, 1005, 1010, 1050, 1055, 1060, 1100, 1105, 1110};

  int tid = threadIdx.x;
  int blk = blockIdx.x;
  int b = blk & 7;                 // XCD-swizzle: one batch per XCD (L2 locality for wmod)
  int tile = blk >> 3;             // 128 tiles
  int z0 = (tile >> 4) * TZ;
  int y0 = ((tile >> 2) & 3) * TY;
  int x0 = (tile & 3) * TXW;

  // ---- staging precompute: 5 chunks of 16B per thread (2400 = 600 rows x 4 quads) ----
  int soff[5];   // bf16x8-unit offset from wsbase (cc adds +4 per chunk step)
  int sl[5];     // LDS bf16-elem offset
#pragma unroll
  for (int i = 0; i < 5; i++) {
    int s = i * 512 + tid;
    if (s < HVOL * 4) {
      int h = s >> 2, q = s & 3;
      int hz = h / 100; int r = h - hz * 100;
      int hy = r / 10;  int hx = r - hy * 10;
      int zz = z0 + hz - 1, yy = y0 + hy - 1, xx = x0 + hx - 1;
      bool ok = ((unsigned)zz < NRES) & ((unsigned)yy < NRES) & ((unsigned)xx < NRES);
      int off = zz * 1024 + yy * 32 + xx;
      soff[i] = ok ? (XT_UNIT + ((size_t)b * NSP + off) * 16 + q) : ZP_UNIT;
      sl[i] = h * CSTR + q * 8;
    } else {
      soff[i] = ZP_UNIT;
      sl[i] = HVOL * CSTR;         // dummy slot
    }
  }

  int lane = tid & 63;
  int wid = tid >> 6;
  int wm = wid >> 2;   // 0..1  cout group
  int wn = wid & 3;    // 0..3  spatial group
  int l15 = lane & 15;
  int g = lane >> 4;

  int hb5[4], sp[4];
#pragma unroll
  for (int ni = 0; ni < 4; ni++) {
    int n = wn * 64 + ni * 16 + l15;
    int dz = n >> 6, dy = (n >> 3) & 7, dx = n & 7;
    hb5[ni] = (dz * 100 + dy * 10 + dx) * 5;
    sp[ni] = dz * 1024 + dy * 32 + dx;
  }
  int arowv[4];
#pragma unroll
  for (int mi = 0; mi < 4; mi++)
    arowv[mi] = (wm * 64 + mi * 16 + l15) * (CIN / 8) + g;

  f32x4 acc[4][4];
#pragma unroll
  for (int mi = 0; mi < 4; mi++)
#pragma unroll
    for (int ni = 0; ni < 4; ni++) acc[mi][ni] = (f32x4){0.f, 0.f, 0.f, 0.f};

  const bf16x8* ap = (const bf16x8*)(wmod + (size_t)b * NTAPS * COUT * CIN);
  const bf16x8* bp = (const bf16x8*)xs;

  // prologue: issue cc=0 staging loads
  bf16x8 sreg[5];
#pragma unroll
  for (int i = 0; i < 5; i++) sreg[i] = wsbase[soff[i]];

#pragma unroll 1
  for (int cc = 0; cc < NCC; cc++) {
    int cc4 = cc * 4;
    __syncthreads();               // xs free
    // A-prefetch for tap 0 (LDS-independent, hides under barrier+writes)
    bf16x8 a[4], bv[4], an[4], bn[4];
#pragma unroll
    for (int mi = 0; mi < 4; mi++) a[mi] = ap[cc4 + arowv[mi]];
#pragma unroll
    for (int i = 0; i < 5; i++) *(bf16x8*)&xs[sl[i]] = sreg[i];
    __syncthreads();
    // T14: issue next chunk's staging loads; drain under the tap loop
    if (cc < NCC - 1) {
#pragma unroll
      for (int i = 0; i < 5; i++) sreg[i] = wsbase[soff[i] + (cc + 1) * 4];
    }
#pragma unroll
    for (int ni = 0; ni < 4; ni++) bv[ni] = bp[hb5[ni] + g];   // tap0 (TOFF5[0]=0)

#pragma unroll
    for (int t = 0; t < NTAPS; t++) {
      if (t < NTAPS - 1) {
        int tb = (t + 1) * 2048 + cc4;
        int tof = TOFF5[t + 1];
#pragma unroll
        for (int mi = 0; mi < 4; mi++) an[mi] = ap[tb + arowv[mi]];
#pragma unroll
        for (int ni = 0; ni < 4; ni++) bn[ni] = bp[hb5[ni] + tof + g];
      }
#pragma unroll
      for (int mi = 0; mi < 4; mi++)
#pragma unroll
        for (int ni = 0; ni < 4; ni++)
          acc[mi][ni] = __builtin_amdgcn_mfma_f32_16x16x32_bf16(
              a[mi], bv[ni], acc[mi][ni], 0, 0, 0);
#pragma unroll
      for (int mi = 0; mi < 4; mi++) a[mi] = an[mi];
#pragma unroll
      for (int ni = 0; ni < 4; ni++) bv[ni] = bn[ni];
    }
  }

  // epilogue: cout = wm*64 + mi*16 + g*4 + r ; spatial n
  size_t obase0 = (size_t)(b * COUT + wm * 64 + g * 4) * NSP +
                  (size_t)(z0 * 1024 + y0 * 32 + x0);
#pragma unroll
  for (int mi = 0; mi < 4; mi++) {
    int c4 = wm * 64 + mi * 16 + g * 4;
    float4 bsv = *(const float4*)(bias + c4);
    float bs[4] = {bsv.x, bsv.y, bsv.z, bsv.w};
#pragma unroll
    for (int ni = 0; ni < 4; ni++) {
#pragma unroll
      for (int r = 0; r < 4; r++) {
        float v = acc[mi][ni][r] + bs[r];
        v = (v >= 0.f ? v : v * 0.2f) * 1.41421356237309515f;
        out[obase0 + (size_t)(mi * 16 + r) * NSP + sp[ni]] = v;
      }
    }
  }
}

extern "C" void kernel_launch(void* const* d_in, const int* in_sizes, int n_in,
                              void* d_out, int out_size, void* d_ws, size_t ws_size,
                              hipStream_t stream) {
  const float* x      = (const float*)d_in[0];
  const float* w      = (const float*)d_in[1];
  const float* weight = (const float*)d_in[2];
  const float* aw     = (const float*)d_in[3];
  const float* ab     = (const float*)d_in[4];
  const float* bias   = (const float*)d_in[5];
  float* out = (float*)d_out;

  float* styles = (float*)d_ws;
  float* zeropad = (float*)((char*)d_ws + 4096);
  __hip_bfloat16* xt = (__hip_bfloat16*)((char*)d_ws + 8192);
  __hip_bfloat16* wmod = (__hip_bfloat16*)((char*)d_ws + 8192 + 67108864);

  k_styles<<<8, 128, 0, stream>>>(w, aw, ab, styles, zeropad);
  k_wmod<<<8 * 128, 256, 0, stream>>>(weight, styles, wmod);
  k_xt<<<8 * 512, 256, 0, stream>>>(x, xt);
  k_conv<<<8 * 128, 512, 0, stream>>>((const bf16x8*)d_ws, wmod, bias, out);
}

// Round 3
// 323.963 us; speedup vs baseline: 2.6133x; 2.6133x over previous
//
#include <hip/hip_runtime.h>
#include <hip/hip_bf16.h>

typedef __attribute__((ext_vector_type(8))) short bf16x8;   // 8 bf16 = 4 VGPRs
typedef __attribute__((ext_vector_type(4))) float f32x4;

#define WDIM 512
#define CIN 128
#define COUT 128
#define NRES 32
#define NSP 32768          // 32^3
#define NTAPS 27

#define ROWB 2112          // LDS bytes per (z,y) halo row: 32 hx * 64 B + 64 B zero col
#define LDSROWS 16         // 4 hz * 4 hy

// ws layout (bytes):
//   [0,4096)        styles f32[8][128]
//   [4096,8192)     zeropad (zeroed by k_styles)
//   [8192,+64 MiB)  xt bf16 [8][4cc][32768 sp][32 cin]
//   [+64MiB, +6.75MiB) wmod bf16 [8][4cc][128 cout][27 tap][32 cin]
#define ZP_OFF 4096
#define XT_OFF 8192
#define WM_OFF (8192 + 67108864)

typedef __attribute__((address_space(1))) const unsigned int gu32;
typedef __attribute__((address_space(3))) unsigned int lu32;

// ---------------- kernel 1: styles + zero the pad region ----------------
__global__ void k_styles(const float* __restrict__ w,
                         const float* __restrict__ aw,
                         const float* __restrict__ ab,
                         float* __restrict__ styles,
                         float* __restrict__ zeropad) {
  int b = blockIdx.x;      // 8
  int c = threadIdx.x;     // 128
  if (b == 0) {
#pragma unroll
    for (int i = 0; i < 8; i++) zeropad[i * 128 + c] = 0.f;  // 4096 B
  }
  const float4* wr = (const float4*)(w + (size_t)b * WDIM);
  const float4* ar = (const float4*)(aw + (size_t)c * WDIM);
  float s = 0.f;
#pragma unroll 8
  for (int k = 0; k < WDIM / 4; k++) {
    float4 wv = wr[k], av = ar[k];
    s += wv.x * av.x + wv.y * av.y + wv.z * av.z + wv.w * av.w;
  }
  styles[b * CIN + c] = s * 0.04419417382415922f + ab[c];  // 1/sqrt(512)
}

// ---- kernel 2: modulate+demodulate -> bf16 wmod[b][cc][cout][tap][cin32] ----
__global__ void k_wmod(const float* __restrict__ weight,
                       const float* __restrict__ styles,
                       __hip_bfloat16* __restrict__ wmod) {
  int b = blockIdx.x >> 7;
  int co = blockIdx.x & 127;
  __shared__ float st[CIN];
  __shared__ float red[4];
  int tid = threadIdx.x;   // 256
  if (tid < CIN) st[tid] = styles[b * CIN + tid];
  __syncthreads();
  const float* wr = weight + (size_t)co * (CIN * NTAPS);  // [cin][27] for this cout
  float ss = 0.f;
  for (int o = tid; o < CIN * NTAPS; o += 256) {
    float v = wr[o] * st[o / NTAPS];
    ss += v * v;
  }
#pragma unroll
  for (int off = 32; off > 0; off >>= 1) ss += __shfl_down(ss, off);
  if ((tid & 63) == 0) red[tid >> 6] = ss;
  __syncthreads();
  float d = rsqrtf(red[0] + red[1] + red[2] + red[3] + 1e-8f);
  for (int o = tid; o < CIN * NTAPS; o += 256) {
    int t = o >> 7;
    int cin = o & 127;
    float v = wr[cin * NTAPS + t] * st[cin] * d;
    int cc = cin >> 5, cl = cin & 31;
    wmod[((((size_t)(b * 4 + cc) * COUT + co) * NTAPS + t) << 5) + cl] =
        __float2bfloat16(v);
  }
}

// ---- kernel 2.5: x f32 [b][cin][sp] -> xt bf16 [b][cc][sp][cin32] ----
__global__ __launch_bounds__(256)
void k_xt(const float* __restrict__ x, __hip_bfloat16* __restrict__ xt) {
  __shared__ __align__(16) float ts[32][524];   // 67 KB, pad for phase-2 conflicts
  int t = threadIdx.x;
  int blk = blockIdx.x;            // 8 b * 4 cc * 64 spchunks
  int b = blk >> 8, cc = (blk >> 6) & 3, sp0 = (blk & 63) << 9;
  const float* xb = x + (size_t)b * CIN * NSP + (size_t)cc * 32 * NSP + sp0;
#pragma unroll
  for (int i = 0; i < 16; i++) {
    int idx = i * 256 + t;
    int cin = idx >> 7, spq = idx & 127;
    float4 v = *(const float4*)(xb + (size_t)cin * NSP + spq * 4);
    *(float4*)&ts[cin][spq * 4] = v;
  }
  __syncthreads();
  __hip_bfloat16* ob = xt + ((size_t)(b * 4 + cc) * NSP + sp0) * 32;
#pragma unroll
  for (int j = 0; j < 8; j++) {
    int chunk = j * 256 + t;
    int sp_l = chunk >> 2, q = chunk & 3;
    union { bf16x8 v; __hip_bfloat16 h[8]; } u;
#pragma unroll
    for (int k = 0; k < 8; k++) u.h[k] = __float2bfloat16(ts[q * 8 + k][sp_l]);
    *(bf16x8*)(ob + (size_t)sp_l * 32 + q * 8) = u.v;
  }
}

// ---------------- kernel 3: implicit-GEMM conv + bias + lrelu*sqrt(2) ----------------
// 256 thr = 4 waves (2m x 2n); tile M=128 cout x N=128 sp (2z x 2y x 32x)
__global__ __launch_bounds__(256, 3)
void k_conv(const char* __restrict__ ws,
            const float* __restrict__ bias,
            float* __restrict__ out) {
  __shared__ __align__(16) char xs[LDSROWS * ROWB];   // 33792 B

  int tid = threadIdx.x;
  int lane = tid & 63, w = tid >> 6;
  int l15 = lane & 15, g = lane >> 4;
  int wm = w >> 1, wn = w & 1;
  int blk = blockIdx.x;
  int b = blk & 7;                 // one batch per XCD (wmod/xt L2 locality)
  int tile = blk >> 3;             // 16 tz * 16 ty
  int z0 = (tile >> 4) * 2, y0 = (tile & 15) * 2;

  // zero column init: 16 rows x 64 B at row byte offset 2048
  *(int*)&xs[(tid >> 4) * ROWB + 2048 + (tid & 15) * 4] = 0;

  // ---- staging tables: 2048 16-B chunks per cc, 8 iters x 256 thr ----
  int soff[8], sdst[8], svalid[8];
#pragma unroll
  for (int i = 0; i < 8; i++) {
    int c = i * 256 + tid;
    int zy = c >> 7;                       // wave-uniform
    int hz = zy >> 2, hy = zy & 3;
    int zz = z0 + hz - 1, yy = y0 + hy - 1;
    svalid[i] = ((unsigned)zz < NRES) & ((unsigned)yy < NRES);
    int p = c & 127, hx = p >> 2, pos = p & 3;
    int q = pos ^ ((hx >> 1) & 3);         // pre-swizzled global source (rule #21)
    soff[i] = (zz * 1024 + yy * 32 + hx) * 4 + q;   // 16-B units within xt[b][cc]
    sdst[i] = zy * ROWB + (p >> 6) * 1024;          // linear wave-uniform LDS dest
  }

  // ---- fragment LDS addrs: vaddr[ni][tdx], OOB x -> zero column (hx=32) ----
  int vaddr[4][3];
#pragma unroll
  for (int ni = 0; ni < 4; ni++)
#pragma unroll
    for (int tx = 0; tx < 3; tx++) {
      int dx = (ni & 1) * 16 + l15;
      int hx = dx + tx - 1;
      int hxc = ((unsigned)hx > 31u) ? 32 : hx;
      int pos = g ^ ((hxc >> 1) & 3);
      vaddr[ni][tx] = (wn * 4 + (ni >> 1)) * ROWB + hxc * 64 + pos * 16;
    }

  // ---- A chunk bases: wmod chunks idx = ((b*4+cc)*128 + cout)*108 + tap*4 + g ----
  const bf16x8* ap = (const bf16x8*)(ws + WM_OFF);
  int abase[4];
#pragma unroll
  for (int mi = 0; mi < 4; mi++)
    abase[mi] = (wm * 64 + mi * 16 + l15) * 108 + g;

  f32x4 acc[4][4];
#pragma unroll
  for (int mi = 0; mi < 4; mi++)
#pragma unroll
    for (int ni = 0; ni < 4; ni++) acc[mi][ni] = (f32x4){0.f, 0.f, 0.f, 0.f};

  const char* zpg = ws + ZP_OFF;
  const char* xtb = ws + XT_OFF + (size_t)b * (4 * NSP * 64);

#pragma unroll 1
  for (int cc = 0; cc < 4; cc++) {
    const char* xtc = xtb + (size_t)cc * (NSP * 64);
    __syncthreads();                       // previous readers done (covers zero-init on cc=0)
#pragma unroll
    for (int i = 0; i < 8; i++) {
      const char* src = svalid[i] ? (xtc + ((size_t)(unsigned)soff[i] << 4))
                                  : (zpg + lane * 16);
      __builtin_amdgcn_global_load_lds((gu32*)src, (lu32*)(xs + sdst[i]), 16, 0, 0);
    }
    __syncthreads();                       // compiler drains vmcnt(0) here

    int sab = ((b * 4 + cc) * 128) * 108;
    int abc0 = sab + abase[0], abc1 = sab + abase[1];
    int abc2 = sab + abase[2], abc3 = sab + abase[3];

#pragma unroll
    for (int tz = 0; tz < 3; tz++)
#pragma unroll
      for (int ty2 = 0; ty2 < 3; ty2++) {
        const int lit = (tz * 4 + ty2) * ROWB;       // folds into ds offset imm
        const int tapb = (tz * 9 + ty2 * 3) * 4;     // folds into global offset imm
#pragma unroll
        for (int tx = 0; tx < 3; tx++) {
          bf16x8 a0 = ap[abc0 + tapb + tx * 4];
          bf16x8 a1 = ap[abc1 + tapb + tx * 4];
          bf16x8 a2 = ap[abc2 + tapb + tx * 4];
          bf16x8 a3 = ap[abc3 + tapb + tx * 4];
          bf16x8 b0 = *(const bf16x8*)(xs + vaddr[0][tx] + lit);
          bf16x8 b1 = *(const bf16x8*)(xs + vaddr[1][tx] + lit);
          bf16x8 b2 = *(const bf16x8*)(xs + vaddr[2][tx] + lit);
          bf16x8 b3 = *(const bf16x8*)(xs + vaddr[3][tx] + lit);
          acc[0][0] = __builtin_amdgcn_mfma_f32_16x16x32_bf16(a0, b0, acc[0][0], 0, 0, 0);
          acc[0][1] = __builtin_amdgcn_mfma_f32_16x16x32_bf16(a0, b1, acc[0][1], 0, 0, 0);
          acc[0][2] = __builtin_amdgcn_mfma_f32_16x16x32_bf16(a0, b2, acc[0][2], 0, 0, 0);
          acc[0][3] = __builtin_amdgcn_mfma_f32_16x16x32_bf16(a0, b3, acc[0][3], 0, 0, 0);
          acc[1][0] = __builtin_amdgcn_mfma_f32_16x16x32_bf16(a1, b0, acc[1][0], 0, 0, 0);
          acc[1][1] = __builtin_amdgcn_mfma_f32_16x16x32_bf16(a1, b1, acc[1][1], 0, 0, 0);
          acc[1][2] = __builtin_amdgcn_mfma_f32_16x16x32_bf16(a1, b2, acc[1][2], 0, 0, 0);
          acc[1][3] = __builtin_amdgcn_mfma_f32_16x16x32_bf16(a1, b3, acc[1][3], 0, 0, 0);
          acc[2][0] = __builtin_amdgcn_mfma_f32_16x16x32_bf16(a2, b0, acc[2][0], 0, 0, 0);
          acc[2][1] = __builtin_amdgcn_mfma_f32_16x16x32_bf16(a2, b1, acc[2][1], 0, 0, 0);
          acc[2][2] = __builtin_amdgcn_mfma_f32_16x16x32_bf16(a2, b2, acc[2][2], 0, 0, 0);
          acc[2][3] = __builtin_amdgcn_mfma_f32_16x16x32_bf16(a2, b3, acc[2][3], 0, 0, 0);
          acc[3][0] = __builtin_amdgcn_mfma_f32_16x16x32_bf16(a3, b0, acc[3][0], 0, 0, 0);
          acc[3][1] = __builtin_amdgcn_mfma_f32_16x16x32_bf16(a3, b1, acc[3][1], 0, 0, 0);
          acc[3][2] = __builtin_amdgcn_mfma_f32_16x16x32_bf16(a3, b2, acc[3][2], 0, 0, 0);
          acc[3][3] = __builtin_amdgcn_mfma_f32_16x16x32_bf16(a3, b3, acc[3][3], 0, 0, 0);
        }
      }
  }

  // epilogue: cout = wm*64 + mi*16 + g*4 + r ; sp = (z0+wn, y0+(ni>>1), (ni&1)*16+l15)
  size_t ob = ((size_t)(b * COUT + wm * 64 + g * 4)) * NSP +
              (size_t)(z0 + wn) * 1024 + (size_t)y0 * 32;
#pragma unroll
  for (int mi = 0; mi < 4; mi++) {
    float4 bsv = *(const float4*)(bias + wm * 64 + mi * 16 + g * 4);
    float bs[4] = {bsv.x, bsv.y, bsv.z, bsv.w};
#pragma unroll
    for (int ni = 0; ni < 4; ni++) {
      int spo = (ni >> 1) * 32 + (ni & 1) * 16 + l15;
#pragma unroll
      for (int r = 0; r < 4; r++) {
        float v = acc[mi][ni][r] + bs[r];
        v = (v >= 0.f ? v : v * 0.2f) * 1.41421356237309515f;
        out[ob + (size_t)(mi * 16 + r) * NSP + spo] = v;
      }
    }
  }
}

extern "C" void kernel_launch(void* const* d_in, const int* in_sizes, int n_in,
                              void* d_out, int out_size, void* d_ws, size_t ws_size,
                              hipStream_t stream) {
  const float* x      = (const float*)d_in[0];
  const float* w      = (const float*)d_in[1];
  const float* weight = (const float*)d_in[2];
  const float* aw     = (const float*)d_in[3];
  const float* ab     = (const float*)d_in[4];
  const float* bias   = (const float*)d_in[5];
  float* out = (float*)d_out;

  float* styles = (float*)d_ws;
  float* zeropad = (float*)((char*)d_ws + ZP_OFF);
  __hip_bfloat16* xt = (__hip_bfloat16*)((char*)d_ws + XT_OFF);
  __hip_bfloat16* wmod = (__hip_bfloat16*)((char*)d_ws + WM_OFF);

  k_styles<<<8, 128, 0, stream>>>(w, aw, ab, styles, zeropad);
  k_wmod<<<8 * 128, 256, 0, stream>>>(weight, styles, wmod);
  k_xt<<<8 * 4 * 64, 256, 0, stream>>>(x, xt);
  k_conv<<<8 * 256, 256, 0, stream>>>((const char*)d_ws, bias, out);
}

// Round 4
// 314.217 us; speedup vs baseline: 2.6944x; 1.0310x over previous
//
#include <hip/hip_runtime.h>
#include <hip/hip_bf16.h>

typedef __attribute__((ext_vector_type(8))) short bf16x8;   // 8 bf16 = 4 VGPRs
typedef __attribute__((ext_vector_type(4))) float f32x4;

#define WDIM 512
#define CIN 128
#define COUT 128
#define NRES 32
#define NSP 32768          // 32^3
#define NTAPS 27

#define ROWB 2112          // LDS bytes per (z,y) halo row: 32 hx * 64 B + 64 B zero col
#define LDSROWS 16         // 4 hz * 4 hy
#define BUFB (LDSROWS * ROWB)   // 33792 B per buffer; double-buffered

// ws layout (bytes):
//   [0,4096)        styles f32[8][128]
//   [4096,8192)     zeropad (zeroed by k_styles)
//   [8192,+64 MiB)  xt bf16 [8][4cc][32768 sp][32 cin]
//   [+64MiB, +6.75MiB) wmod bf16 [8][4cc][128 cout][27 tap][32 cin]
#define ZP_OFF 4096
#define XT_OFF 8192
#define WM_OFF (8192 + 67108864)

typedef __attribute__((address_space(1))) const unsigned int gu32;
typedef __attribute__((address_space(3))) unsigned int lu32;

// ---------------- kernel 1: styles + zero the pad region ----------------
__global__ void k_styles(const float* __restrict__ w,
                         const float* __restrict__ aw,
                         const float* __restrict__ ab,
                         float* __restrict__ styles,
                         float* __restrict__ zeropad) {
  int b = blockIdx.x;      // 8
  int c = threadIdx.x;     // 128
  if (b == 0) {
#pragma unroll
    for (int i = 0; i < 8; i++) zeropad[i * 128 + c] = 0.f;  // 4096 B
  }
  const float4* wr = (const float4*)(w + (size_t)b * WDIM);
  const float4* ar = (const float4*)(aw + (size_t)c * WDIM);
  float s = 0.f;
#pragma unroll 8
  for (int k = 0; k < WDIM / 4; k++) {
    float4 wv = wr[k], av = ar[k];
    s += wv.x * av.x + wv.y * av.y + wv.z * av.z + wv.w * av.w;
  }
  styles[b * CIN + c] = s * 0.04419417382415922f + ab[c];  // 1/sqrt(512)
}

// ---- kernel 2: modulate+demodulate -> bf16 wmod[b][cc][cout][tap][cin32] ----
__global__ void k_wmod(const float* __restrict__ weight,
                       const float* __restrict__ styles,
                       __hip_bfloat16* __restrict__ wmod) {
  int b = blockIdx.x >> 7;
  int co = blockIdx.x & 127;
  __shared__ float st[CIN];
  __shared__ float red[4];
  int tid = threadIdx.x;   // 256
  if (tid < CIN) st[tid] = styles[b * CIN + tid];
  __syncthreads();
  const float* wr = weight + (size_t)co * (CIN * NTAPS);  // [cin][27] for this cout
  float ss = 0.f;
  for (int o = tid; o < CIN * NTAPS; o += 256) {
    float v = wr[o] * st[o / NTAPS];
    ss += v * v;
  }
#pragma unroll
  for (int off = 32; off > 0; off >>= 1) ss += __shfl_down(ss, off);
  if ((tid & 63) == 0) red[tid >> 6] = ss;
  __syncthreads();
  float d = rsqrtf(red[0] + red[1] + red[2] + red[3] + 1e-8f);
  for (int o = tid; o < CIN * NTAPS; o += 256) {
    int t = o >> 7;
    int cin = o & 127;
    float v = wr[cin * NTAPS + t] * st[cin] * d;
    int cc = cin >> 5, cl = cin & 31;
    wmod[((((size_t)(b * 4 + cc) * COUT + co) * NTAPS + t) << 5) + cl] =
        __float2bfloat16(v);
  }
}

// ---- kernel 2.5: x f32 [b][cin][sp] -> xt bf16 [b][cc][sp][cin32] ----
__global__ __launch_bounds__(256)
void k_xt(const float* __restrict__ x, __hip_bfloat16* __restrict__ xt) {
  __shared__ __align__(16) float ts[32][524];   // 67 KB, pad for phase-2 conflicts
  int t = threadIdx.x;
  int blk = blockIdx.x;            // 8 b * 4 cc * 64 spchunks
  int b = blk >> 8, cc = (blk >> 6) & 3, sp0 = (blk & 63) << 9;
  const float* xb = x + (size_t)b * CIN * NSP + (size_t)cc * 32 * NSP + sp0;
#pragma unroll
  for (int i = 0; i < 16; i++) {
    int idx = i * 256 + t;
    int cin = idx >> 7, spq = idx & 127;
    float4 v = *(const float4*)(xb + (size_t)cin * NSP + spq * 4);
    *(float4*)&ts[cin][spq * 4] = v;
  }
  __syncthreads();
  __hip_bfloat16* ob = xt + ((size_t)(b * 4 + cc) * NSP + sp0) * 32;
#pragma unroll
  for (int j = 0; j < 8; j++) {
    int chunk = j * 256 + t;
    int sp_l = chunk >> 2, q = chunk & 3;
    union { bf16x8 v; __hip_bfloat16 h[8]; } u;
#pragma unroll
    for (int k = 0; k < 8; k++) u.h[k] = __float2bfloat16(ts[q * 8 + k][sp_l]);
    *(bf16x8*)(ob + (size_t)sp_l * 32 + q * 8) = u.v;
  }
}

// ---------------- kernel 3: implicit-GEMM conv + bias + lrelu*sqrt(2) ----------------
// 256 thr = 4 waves (2m x 2n); tile M=128 cout x N=128 sp (2z x 2y x 32x)
// LDS double-buffered: stage(cc+1) issued before compute(cc); one barrier per cc.
__global__ __launch_bounds__(256, 2)
void k_conv(const char* __restrict__ ws,
            const float* __restrict__ bias,
            float* __restrict__ out) {
  extern __shared__ __align__(16) char xs[];   // 2 * 33792 B

  int tid = threadIdx.x;
  int lane = tid & 63, w = tid >> 6;
  int l15 = lane & 15, g = lane >> 4;
  int wm = w >> 1, wn = w & 1;
  int blk = blockIdx.x;
  int b = blk & 7;                 // one batch per XCD (wmod/xt L2 locality)
  int tile = blk >> 3;             // 16 tz * 16 ty
  int z0 = (tile >> 4) * 2, y0 = (tile & 15) * 2;

  // zero column init (both buffers): 16 rows x 64 B at row byte offset 2048
  {
    int r16 = tid >> 4, c16 = (tid & 15) * 4;
    *(int*)&xs[r16 * ROWB + 2048 + c16] = 0;
    *(int*)&xs[BUFB + r16 * ROWB + 2048 + c16] = 0;
  }

  // ---- staging tables: 2048 16-B chunks per cc, 8 iters x 256 thr ----
  int soff[8], sdst[8], svalid[8];
#pragma unroll
  for (int i = 0; i < 8; i++) {
    int c = i * 256 + tid;
    int zy = c >> 7;                       // wave-uniform
    int hz = zy >> 2, hy = zy & 3;
    int zz = z0 + hz - 1, yy = y0 + hy - 1;
    svalid[i] = ((unsigned)zz < NRES) & ((unsigned)yy < NRES);
    int p = c & 127, hx = p >> 2, pos = p & 3;
    int q = pos ^ ((hx >> 1) & 3);         // pre-swizzled global source (rule #21)
    soff[i] = (zz * 1024 + yy * 32 + hx) * 4 + q;   // 16-B units within xt[b][cc]
    sdst[i] = zy * ROWB + (p >> 6) * 1024;          // linear wave-uniform LDS dest
  }

  // ---- fragment LDS addrs: vaddr[ni][tdx], OOB x -> zero column (hx=32) ----
  int vaddr[4][3];
#pragma unroll
  for (int ni = 0; ni < 4; ni++)
#pragma unroll
    for (int tx = 0; tx < 3; tx++) {
      int dx = (ni & 1) * 16 + l15;
      int hx = dx + tx - 1;
      int hxc = ((unsigned)hx > 31u) ? 32 : hx;
      int pos = g ^ ((hxc >> 1) & 3);
      vaddr[ni][tx] = (wn * 4 + (ni >> 1)) * ROWB + hxc * 64 + pos * 16;
    }

  // ---- A chunk bases: wmod chunks idx = ((b*4+cc)*128 + cout)*108 + tap*4 + g ----
  const bf16x8* ap = (const bf16x8*)(ws + WM_OFF);
  int abase[4];
#pragma unroll
  for (int mi = 0; mi < 4; mi++)
    abase[mi] = (wm * 64 + mi * 16 + l15) * 108 + g;

  f32x4 acc[4][4];
#pragma unroll
  for (int mi = 0; mi < 4; mi++)
#pragma unroll
    for (int ni = 0; ni < 4; ni++) acc[mi][ni] = (f32x4){0.f, 0.f, 0.f, 0.f};

  const char* zpg = ws + ZP_OFF;
  const char* xtb = ws + XT_OFF + (size_t)b * (4 * NSP * 64);

  auto stage = [&](char* dst, const char* xtc) {
#pragma unroll
    for (int i = 0; i < 8; i++) {
      const char* src = svalid[i] ? (xtc + ((size_t)(unsigned)soff[i] << 4))
                                  : (zpg + lane * 16);
      __builtin_amdgcn_global_load_lds((gu32*)src, (lu32*)(dst + sdst[i]), 16, 0, 0);
    }
  };

  // prologue: stage cc=0 into buf0; barrier drains vmcnt + makes zero-col visible
  stage(xs, xtb);
  __syncthreads();

#pragma unroll 1
  for (int cc = 0; cc < 4; cc++) {
    // T14/T3: issue next chunk's staging first; it drains under this cc's MFMAs
    if (cc < 3)
      stage(xs + ((cc + 1) & 1) * BUFB, xtb + (size_t)(cc + 1) * (NSP * 64));
    const char* xsb = xs + (cc & 1) * BUFB;

    int sab = ((b * 4 + cc) * 128) * 108;
    int abc0 = sab + abase[0], abc1 = sab + abase[1];
    int abc2 = sab + abase[2], abc3 = sab + abase[3];

#pragma unroll
    for (int tz = 0; tz < 3; tz++)
#pragma unroll
      for (int ty2 = 0; ty2 < 3; ty2++) {
        const int lit = (tz * 4 + ty2) * ROWB;       // folds into ds offset imm
        const int tapb = (tz * 9 + ty2 * 3) * 4;     // folds into global offset imm
#pragma unroll
        for (int tx = 0; tx < 3; tx++) {
          bf16x8 a0 = ap[abc0 + tapb + tx * 4];
          bf16x8 a1 = ap[abc1 + tapb + tx * 4];
          bf16x8 a2 = ap[abc2 + tapb + tx * 4];
          bf16x8 a3 = ap[abc3 + tapb + tx * 4];
          bf16x8 b0 = *(const bf16x8*)(xsb + vaddr[0][tx] + lit);
          bf16x8 b1 = *(const bf16x8*)(xsb + vaddr[1][tx] + lit);
          bf16x8 b2 = *(const bf16x8*)(xsb + vaddr[2][tx] + lit);
          bf16x8 b3 = *(const bf16x8*)(xsb + vaddr[3][tx] + lit);
          __builtin_amdgcn_s_setprio(1);
          acc[0][0] = __builtin_amdgcn_mfma_f32_16x16x32_bf16(a0, b0, acc[0][0], 0, 0, 0);
          acc[0][1] = __builtin_amdgcn_mfma_f32_16x16x32_bf16(a0, b1, acc[0][1], 0, 0, 0);
          acc[0][2] = __builtin_amdgcn_mfma_f32_16x16x32_bf16(a0, b2, acc[0][2], 0, 0, 0);
          acc[0][3] = __builtin_amdgcn_mfma_f32_16x16x32_bf16(a0, b3, acc[0][3], 0, 0, 0);
          acc[1][0] = __builtin_amdgcn_mfma_f32_16x16x32_bf16(a1, b0, acc[1][0], 0, 0, 0);
          acc[1][1] = __builtin_amdgcn_mfma_f32_16x16x32_bf16(a1, b1, acc[1][1], 0, 0, 0);
          acc[1][2] = __builtin_amdgcn_mfma_f32_16x16x32_bf16(a1, b2, acc[1][2], 0, 0, 0);
          acc[1][3] = __builtin_amdgcn_mfma_f32_16x16x32_bf16(a1, b3, acc[1][3], 0, 0, 0);
          acc[2][0] = __builtin_amdgcn_mfma_f32_16x16x32_bf16(a2, b0, acc[2][0], 0, 0, 0);
          acc[2][1] = __builtin_amdgcn_mfma_f32_16x16x32_bf16(a2, b1, acc[2][1], 0, 0, 0);
          acc[2][2] = __builtin_amdgcn_mfma_f32_16x16x32_bf16(a2, b2, acc[2][2], 0, 0, 0);
          acc[2][3] = __builtin_amdgcn_mfma_f32_16x16x32_bf16(a2, b3, acc[2][3], 0, 0, 0);
          acc[3][0] = __builtin_amdgcn_mfma_f32_16x16x32_bf16(a3, b0, acc[3][0], 0, 0, 0);
          acc[3][1] = __builtin_amdgcn_mfma_f32_16x16x32_bf16(a3, b1, acc[3][1], 0, 0, 0);
          acc[3][2] = __builtin_amdgcn_mfma_f32_16x16x32_bf16(a3, b2, acc[3][2], 0, 0, 0);
          acc[3][3] = __builtin_amdgcn_mfma_f32_16x16x32_bf16(a3, b3, acc[3][3], 0, 0, 0);
          __builtin_amdgcn_s_setprio(0);
        }
      }
    if (cc < 3) __syncthreads();   // drains staged loads (long since issued) + readers
  }

  // epilogue: cout = wm*64 + mi*16 + g*4 + r ; sp = (z0+wn, y0+(ni>>1), (ni&1)*16+l15)
  size_t ob = ((size_t)(b * COUT + wm * 64 + g * 4)) * NSP +
              (size_t)(z0 + wn) * 1024 + (size_t)y0 * 32;
#pragma unroll
  for (int mi = 0; mi < 4; mi++) {
    float4 bsv = *(const float4*)(bias + wm * 64 + mi * 16 + g * 4);
    float bs[4] = {bsv.x, bsv.y, bsv.z, bsv.w};
#pragma unroll
    for (int ni = 0; ni < 4; ni++) {
      int spo = (ni >> 1) * 32 + (ni & 1) * 16 + l15;
#pragma unroll
      for (int r = 0; r < 4; r++) {
        float v = acc[mi][ni][r] + bs[r];
        v = (v >= 0.f ? v : v * 0.2f) * 1.41421356237309515f;
        out[ob + (size_t)(mi * 16 + r) * NSP + spo] = v;
      }
    }
  }
}

extern "C" void kernel_launch(void* const* d_in, const int* in_sizes, int n_in,
                              void* d_out, int out_size, void* d_ws, size_t ws_size,
                              hipStream_t stream) {
  const float* x      = (const float*)d_in[0];
  const float* w      = (const float*)d_in[1];
  const float* weight = (const float*)d_in[2];
  const float* aw     = (const float*)d_in[3];
  const float* ab     = (const float*)d_in[4];
  const float* bias   = (const float*)d_in[5];
  float* out = (float*)d_out;

  float* styles = (float*)d_ws;
  float* zeropad = (float*)((char*)d_ws + ZP_OFF);
  __hip_bfloat16* xt = (__hip_bfloat16*)((char*)d_ws + XT_OFF);
  __hip_bfloat16* wmod = (__hip_bfloat16*)((char*)d_ws + WM_OFF);

  k_styles<<<8, 128, 0, stream>>>(w, aw, ab, styles, zeropad);
  k_wmod<<<8 * 128, 256, 0, stream>>>(weight, styles, wmod);
  k_xt<<<8 * 4 * 64, 256, 0, stream>>>(x, xt);
  k_conv<<<8 * 256, 256, 2 * BUFB, stream>>>((const char*)d_ws, bias, out);
}

// Round 5
// 303.193 us; speedup vs baseline: 2.7923x; 1.0364x over previous
//
#include <hip/hip_runtime.h>
#include <hip/hip_bf16.h>

typedef __attribute__((ext_vector_type(8))) short bf16x8;   // 8 bf16 = 4 VGPRs
typedef __attribute__((ext_vector_type(4))) float f32x4;

#define WDIM 512
#define CIN 128
#define COUT 128
#define NRES 32
#define NSP 32768          // 32^3
#define NTAPS 27

#define ROWB 2112          // LDS bytes per (z,y) halo row: 32 hx * 64 B + 64 B zero col
#define LDSROWS 16         // 4 hz * 4 hy
#define BUFB (LDSROWS * ROWB)   // 33792 B per buffer; double-buffered

// ws layout (bytes):
//   [0,4096)        styles f32[8][128]
//   [4096,8192)     zeropad (zeroed by k_styles)
//   [8192,+64 MiB)  xt bf16 [8][4cc][32768 sp][32 cin]
//   [+64MiB, +6.75MiB) wmod bf16 [8][4cc][128 cout][27 tap][32 cin]
#define ZP_OFF 4096
#define XT_OFF 8192
#define WM_OFF (8192 + 67108864)

typedef __attribute__((address_space(1))) const unsigned int gu32;
typedef __attribute__((address_space(3))) unsigned int lu32;

// ---------------- kernel 1: styles + zero the pad region ----------------
__global__ void k_styles(const float* __restrict__ w,
                         const float* __restrict__ aw,
                         const float* __restrict__ ab,
                         float* __restrict__ styles,
                         float* __restrict__ zeropad) {
  int b = blockIdx.x;      // 8
  int c = threadIdx.x;     // 128
  if (b == 0) {
#pragma unroll
    for (int i = 0; i < 8; i++) zeropad[i * 128 + c] = 0.f;  // 4096 B
  }
  const float4* wr = (const float4*)(w + (size_t)b * WDIM);
  const float4* ar = (const float4*)(aw + (size_t)c * WDIM);
  float s = 0.f;
#pragma unroll 8
  for (int k = 0; k < WDIM / 4; k++) {
    float4 wv = wr[k], av = ar[k];
    s += wv.x * av.x + wv.y * av.y + wv.z * av.z + wv.w * av.w;
  }
  styles[b * CIN + c] = s * 0.04419417382415922f + ab[c];  // 1/sqrt(512)
}

// ---- kernel 2: modulate+demodulate -> bf16 wmod[b][cc][cout][tap][cin32] ----
__global__ void k_wmod(const float* __restrict__ weight,
                       const float* __restrict__ styles,
                       __hip_bfloat16* __restrict__ wmod) {
  int b = blockIdx.x >> 7;
  int co = blockIdx.x & 127;
  __shared__ float st[CIN];
  __shared__ float red[4];
  int tid = threadIdx.x;   // 256
  if (tid < CIN) st[tid] = styles[b * CIN + tid];
  __syncthreads();
  const float* wr = weight + (size_t)co * (CIN * NTAPS);  // [cin][27] for this cout
  float ss = 0.f;
  for (int o = tid; o < CIN * NTAPS; o += 256) {
    float v = wr[o] * st[o / NTAPS];
    ss += v * v;
  }
#pragma unroll
  for (int off = 32; off > 0; off >>= 1) ss += __shfl_down(ss, off);
  if ((tid & 63) == 0) red[tid >> 6] = ss;
  __syncthreads();
  float d = rsqrtf(red[0] + red[1] + red[2] + red[3] + 1e-8f);
  for (int o = tid; o < CIN * NTAPS; o += 256) {
    int t = o >> 7;
    int cin = o & 127;
    float v = wr[cin * NTAPS + t] * st[cin] * d;
    int cc = cin >> 5, cl = cin & 31;
    wmod[((((size_t)(b * 4 + cc) * COUT + co) * NTAPS + t) << 5) + cl] =
        __float2bfloat16(v);
  }
}

// ---- kernel 2.5: x f32 [b][cin][sp] -> xt bf16 [b][cc][sp][cin32] ----
__global__ __launch_bounds__(256)
void k_xt(const float* __restrict__ x, __hip_bfloat16* __restrict__ xt) {
  __shared__ __align__(16) float ts[32][524];   // 67 KB, pad for phase-2 conflicts
  int t = threadIdx.x;
  int blk = blockIdx.x;            // 8 b * 4 cc * 64 spchunks
  int b = blk >> 8, cc = (blk >> 6) & 3, sp0 = (blk & 63) << 9;
  const float* xb = x + (size_t)b * CIN * NSP + (size_t)cc * 32 * NSP + sp0;
#pragma unroll
  for (int i = 0; i < 16; i++) {
    int idx = i * 256 + t;
    int cin = idx >> 7, spq = idx & 127;
    float4 v = *(const float4*)(xb + (size_t)cin * NSP + spq * 4);
    *(float4*)&ts[cin][spq * 4] = v;
  }
  __syncthreads();
  __hip_bfloat16* ob = xt + ((size_t)(b * 4 + cc) * NSP + sp0) * 32;
#pragma unroll
  for (int j = 0; j < 8; j++) {
    int chunk = j * 256 + t;
    int sp_l = chunk >> 2, q = chunk & 3;
    union { bf16x8 v; __hip_bfloat16 h[8]; } u;
#pragma unroll
    for (int k = 0; k < 8; k++) u.h[k] = __float2bfloat16(ts[q * 8 + k][sp_l]);
    *(bf16x8*)(ob + (size_t)sp_l * 32 + q * 8) = u.v;
  }
}

// ---------------- kernel 3: implicit-GEMM conv + bias + lrelu*sqrt(2) ----------------
// 256 thr = 4 waves (2m x 2n); tile M=128 cout x N=128 sp (2z x 2y x 32x)
// LDS double-buffered. Per cc: prologue loads A(0..1)/B(0..1) BEFORE staging issue
// (vmcnt in-order retirement: waits for taps 0-1 then don't drain staging), then a
// fully-unrolled tap loop with 3-slot rotating A/B register prefetch (2 taps deep).
__global__ __launch_bounds__(256, 2)
void k_conv(const char* __restrict__ ws,
            const float* __restrict__ bias,
            float* __restrict__ out) {
  extern __shared__ __align__(16) char xs[];   // 2 * 33792 B

  int tid = threadIdx.x;
  int lane = tid & 63, w = tid >> 6;
  int l15 = lane & 15, g = lane >> 4;
  int wm = w >> 1, wn = w & 1;
  int blk = blockIdx.x;
  int b = blk & 7;                 // one batch per XCD (wmod/xt L2 locality)
  int tile = blk >> 3;             // 16 tz * 16 ty
  int z0 = (tile >> 4) * 2, y0 = (tile & 15) * 2;

  // zero column init (both buffers): 16 rows x 64 B at row byte offset 2048
  {
    int r16 = tid >> 4, c16 = (tid & 15) * 4;
    *(int*)&xs[r16 * ROWB + 2048 + c16] = 0;
    *(int*)&xs[BUFB + r16 * ROWB + 2048 + c16] = 0;
  }

  // ---- staging tables: 2048 16-B chunks per cc, 8 iters x 256 thr ----
  int soff[8], sdst[8], svalid[8];
#pragma unroll
  for (int i = 0; i < 8; i++) {
    int c = i * 256 + tid;
    int zy = c >> 7;                       // wave-uniform
    int hz = zy >> 2, hy = zy & 3;
    int zz = z0 + hz - 1, yy = y0 + hy - 1;
    svalid[i] = ((unsigned)zz < NRES) & ((unsigned)yy < NRES);
    int p = c & 127, hx = p >> 2, pos = p & 3;
    int q = pos ^ ((hx >> 1) & 3);         // pre-swizzled global source (rule #21)
    soff[i] = (zz * 1024 + yy * 32 + hx) * 4 + q;   // 16-B units within xt[b][cc]
    sdst[i] = zy * ROWB + (p >> 6) * 1024;          // linear wave-uniform LDS dest
  }

  // ---- fragment LDS addrs: vaddr[ni][tx], OOB x -> zero column (hx=32) ----
  int vaddr[4][3];
#pragma unroll
  for (int ni = 0; ni < 4; ni++)
#pragma unroll
    for (int tx = 0; tx < 3; tx++) {
      int dx = (ni & 1) * 16 + l15;
      int hx = dx + tx - 1;
      int hxc = ((unsigned)hx > 31u) ? 32 : hx;
      int pos = g ^ ((hxc >> 1) & 3);
      vaddr[ni][tx] = (wn * 4 + (ni >> 1)) * ROWB + hxc * 64 + pos * 16;
    }

  // ---- A chunk bases: wmod chunks idx = ((b*4+cc)*128 + cout)*108 + tap*4 + g ----
  const bf16x8* ap = (const bf16x8*)(ws + WM_OFF);
  int abase[4];
#pragma unroll
  for (int mi = 0; mi < 4; mi++)
    abase[mi] = (wm * 64 + mi * 16 + l15) * 108 + g;

  f32x4 acc[4][4];
#pragma unroll
  for (int mi = 0; mi < 4; mi++)
#pragma unroll
    for (int ni = 0; ni < 4; ni++) acc[mi][ni] = (f32x4){0.f, 0.f, 0.f, 0.f};

  const char* zpg = ws + ZP_OFF;
  const char* xtb = ws + XT_OFF + (size_t)b * (4 * NSP * 64);

  auto stage = [&](char* dst, const char* xtc) {
#pragma unroll
    for (int i = 0; i < 8; i++) {
      const char* src = svalid[i] ? (xtc + ((size_t)(unsigned)soff[i] << 4))
                                  : (zpg + lane * 16);
      __builtin_amdgcn_global_load_lds((gu32*)src, (lu32*)(dst + sdst[i]), 16, 0, 0);
    }
  };

  // prologue: stage cc=0 into buf0; barrier drains vmcnt + makes zero-col visible
  stage(xs, xtb);
  __syncthreads();

#pragma unroll 1
  for (int cc = 0; cc < 4; cc++) {
    const char* xsb = xs + (cc & 1) * BUFB;
    int sab = ((b * 4 + cc) * 128) * 108;
    int abc0 = sab + abase[0], abc1 = sab + abase[1];
    int abc2 = sab + abase[2], abc3 = sab + abase[3];

    bf16x8 A[3][4], Bv[3][4];
    // ---- cc prologue: A(0),A(1) + B(0),B(1) issued BEFORE staging ----
#pragma unroll
    for (int pt = 0; pt < 2; pt++) {
      A[pt][0] = ap[abc0 + pt * 4];
      A[pt][1] = ap[abc1 + pt * 4];
      A[pt][2] = ap[abc2 + pt * 4];
      A[pt][3] = ap[abc3 + pt * 4];
#pragma unroll
      for (int ni = 0; ni < 4; ni++)
        Bv[pt][ni] = *(const bf16x8*)(xsb + vaddr[ni][pt]);  // taps 0,1: lit=0, tx=pt
    }
    __builtin_amdgcn_sched_barrier(0);     // pin: prologue loads stay before staging
    if (cc < 3)
      stage(xs + ((cc + 1) & 1) * BUFB, xtb + (size_t)(cc + 1) * (NSP * 64));
    __builtin_amdgcn_sched_barrier(0);     // pin: staging stays before tap loop

#pragma unroll
    for (int t = 0; t < NTAPS; t++) {
      if (t + 2 < NTAPS) {
        const int t2 = t + 2;
        const int s2 = t2 % 3;             // == tx of tap t2 (27 = 9*3 layout)
        const int lit2 = ((t2 / 9) * 4 + (t2 / 3) % 3) * ROWB;
        A[s2][0] = ap[abc0 + t2 * 4];
        A[s2][1] = ap[abc1 + t2 * 4];
        A[s2][2] = ap[abc2 + t2 * 4];
        A[s2][3] = ap[abc3 + t2 * 4];
#pragma unroll
        for (int ni = 0; ni < 4; ni++)
          Bv[s2][ni] = *(const bf16x8*)(xsb + vaddr[ni][s2] + lit2);
      }
      const int s = t % 3;
      __builtin_amdgcn_s_setprio(1);
      acc[0][0] = __builtin_amdgcn_mfma_f32_16x16x32_bf16(A[s][0], Bv[s][0], acc[0][0], 0, 0, 0);
      acc[0][1] = __builtin_amdgcn_mfma_f32_16x16x32_bf16(A[s][0], Bv[s][1], acc[0][1], 0, 0, 0);
      acc[0][2] = __builtin_amdgcn_mfma_f32_16x16x32_bf16(A[s][0], Bv[s][2], acc[0][2], 0, 0, 0);
      acc[0][3] = __builtin_amdgcn_mfma_f32_16x16x32_bf16(A[s][0], Bv[s][3], acc[0][3], 0, 0, 0);
      acc[1][0] = __builtin_amdgcn_mfma_f32_16x16x32_bf16(A[s][1], Bv[s][0], acc[1][0], 0, 0, 0);
      acc[1][1] = __builtin_amdgcn_mfma_f32_16x16x32_bf16(A[s][1], Bv[s][1], acc[1][1], 0, 0, 0);
      acc[1][2] = __builtin_amdgcn_mfma_f32_16x16x32_bf16(A[s][1], Bv[s][2], acc[1][2], 0, 0, 0);
      acc[1][3] = __builtin_amdgcn_mfma_f32_16x16x32_bf16(A[s][1], Bv[s][3], acc[1][3], 0, 0, 0);
      acc[2][0] = __builtin_amdgcn_mfma_f32_16x16x32_bf16(A[s][2], Bv[s][0], acc[2][0], 0, 0, 0);
      acc[2][1] = __builtin_amdgcn_mfma_f32_16x16x32_bf16(A[s][2], Bv[s][1], acc[2][1], 0, 0, 0);
      acc[2][2] = __builtin_amdgcn_mfma_f32_16x16x32_bf16(A[s][2], Bv[s][2], acc[2][2], 0, 0, 0);
      acc[2][3] = __builtin_amdgcn_mfma_f32_16x16x32_bf16(A[s][2], Bv[s][3], acc[2][3], 0, 0, 0);
      acc[3][0] = __builtin_amdgcn_mfma_f32_16x16x32_bf16(A[s][3], Bv[s][0], acc[3][0], 0, 0, 0);
      acc[3][1] = __builtin_amdgcn_mfma_f32_16x16x32_bf16(A[s][3], Bv[s][1], acc[3][1], 0, 0, 0);
      acc[3][2] = __builtin_amdgcn_mfma_f32_16x16x32_bf16(A[s][3], Bv[s][2], acc[3][2], 0, 0, 0);
      acc[3][3] = __builtin_amdgcn_mfma_f32_16x16x32_bf16(A[s][3], Bv[s][3], acc[3][3], 0, 0, 0);
      __builtin_amdgcn_s_setprio(0);
    }
    if (cc < 3) __syncthreads();   // staging aged ~25 taps -> drain ~free
  }

  // epilogue: cout = wm*64 + mi*16 + g*4 + r ; sp = (z0+wn, y0+(ni>>1), (ni&1)*16+l15)
  size_t ob = ((size_t)(b * COUT + wm * 64 + g * 4)) * NSP +
              (size_t)(z0 + wn) * 1024 + (size_t)y0 * 32;
#pragma unroll
  for (int mi = 0; mi < 4; mi++) {
    float4 bsv = *(const float4*)(bias + wm * 64 + mi * 16 + g * 4);
    float bs[4] = {bsv.x, bsv.y, bsv.z, bsv.w};
#pragma unroll
    for (int ni = 0; ni < 4; ni++) {
      int spo = (ni >> 1) * 32 + (ni & 1) * 16 + l15;
#pragma unroll
      for (int r = 0; r < 4; r++) {
        float v = acc[mi][ni][r] + bs[r];
        v = (v >= 0.f ? v : v * 0.2f) * 1.41421356237309515f;
        out[ob + (size_t)(mi * 16 + r) * NSP + spo] = v;
      }
    }
  }
}

extern "C" void kernel_launch(void* const* d_in, const int* in_sizes, int n_in,
                              void* d_out, int out_size, void* d_ws, size_t ws_size,
                              hipStream_t stream) {
  const float* x      = (const float*)d_in[0];
  const float* w      = (const float*)d_in[1];
  const float* weight = (const float*)d_in[2];
  const float* aw     = (const float*)d_in[3];
  const float* ab     = (const float*)d_in[4];
  const float* bias   = (const float*)d_in[5];
  float* out = (float*)d_out;

  float* styles = (float*)d_ws;
  float* zeropad = (float*)((char*)d_ws + ZP_OFF);
  __hip_bfloat16* xt = (__hip_bfloat16*)((char*)d_ws + XT_OFF);
  __hip_bfloat16* wmod = (__hip_bfloat16*)((char*)d_ws + WM_OFF);

  k_styles<<<8, 128, 0, stream>>>(w, aw, ab, styles, zeropad);
  k_wmod<<<8 * 128, 256, 0, stream>>>(weight, styles, wmod);
  k_xt<<<8 * 4 * 64, 256, 0, stream>>>(x, xt);
  k_conv<<<8 * 256, 256, 2 * BUFB, stream>>>((const char*)d_ws, bias, out);
}

// Round 6
// 285.759 us; speedup vs baseline: 2.9627x; 1.0610x over previous
//
#include <hip/hip_runtime.h>
#include <hip/hip_bf16.h>

typedef __attribute__((ext_vector_type(8))) short bf16x8;   // 8 bf16 = 4 VGPRs
typedef __attribute__((ext_vector_type(4))) float f32x4;

#define WDIM 512
#define CIN 128
#define COUT 128
#define NRES 32
#define NSP 32768          // 32^3
#define NTAPS 27

#define ROWB 2112          // LDS bytes per (z,y) halo row: 32 hx * 64 B + 64 B zero col
#define LDSROWS 16         // 4 hz * 4 hy

// ws layout (bytes):
//   [0,4096)        styles f32[8][128]
//   [4096,8192)     zeropad (zeroed by k_styles)
//   [8192,+64 MiB)  xt bf16 [8][4cc][32768 sp][32 cin]
//   [+64MiB, +6.75MiB) wmod bf16 [8][4cc][128 cout][27 tap][32 cin]
#define ZP_OFF 4096
#define XT_OFF 8192
#define WM_OFF (8192 + 67108864)

typedef __attribute__((address_space(1))) const unsigned int gu32;
typedef __attribute__((address_space(3))) unsigned int lu32;

// ---------------- kernel 1: styles + zero the pad region ----------------
__global__ void k_styles(const float* __restrict__ w,
                         const float* __restrict__ aw,
                         const float* __restrict__ ab,
                         float* __restrict__ styles,
                         float* __restrict__ zeropad) {
  int b = blockIdx.x;      // 8
  int c = threadIdx.x;     // 128
  if (b == 0) {
#pragma unroll
    for (int i = 0; i < 8; i++) zeropad[i * 128 + c] = 0.f;  // 4096 B
  }
  const float4* wr = (const float4*)(w + (size_t)b * WDIM);
  const float4* ar = (const float4*)(aw + (size_t)c * WDIM);
  float s = 0.f;
#pragma unroll 8
  for (int k = 0; k < WDIM / 4; k++) {
    float4 wv = wr[k], av = ar[k];
    s += wv.x * av.x + wv.y * av.y + wv.z * av.z + wv.w * av.w;
  }
  styles[b * CIN + c] = s * 0.04419417382415922f + ab[c];  // 1/sqrt(512)
}

// ---- kernel 2: modulate+demodulate -> bf16 wmod[b][cc][cout][tap][cin32] ----
__global__ void k_wmod(const float* __restrict__ weight,
                       const float* __restrict__ styles,
                       __hip_bfloat16* __restrict__ wmod) {
  int b = blockIdx.x >> 7;
  int co = blockIdx.x & 127;
  __shared__ float st[CIN];
  __shared__ float red[4];
  int tid = threadIdx.x;   // 256
  if (tid < CIN) st[tid] = styles[b * CIN + tid];
  __syncthreads();
  const float* wr = weight + (size_t)co * (CIN * NTAPS);  // [cin][27] for this cout
  float ss = 0.f;
  for (int o = tid; o < CIN * NTAPS; o += 256) {
    float v = wr[o] * st[o / NTAPS];
    ss += v * v;
  }
#pragma unroll
  for (int off = 32; off > 0; off >>= 1) ss += __shfl_down(ss, off);
  if ((tid & 63) == 0) red[tid >> 6] = ss;
  __syncthreads();
  float d = rsqrtf(red[0] + red[1] + red[2] + red[3] + 1e-8f);
  for (int o = tid; o < CIN * NTAPS; o += 256) {
    int t = o >> 7;
    int cin = o & 127;
    float v = wr[cin * NTAPS + t] * st[cin] * d;
    int cc = cin >> 5, cl = cin & 31;
    wmod[((((size_t)(b * 4 + cc) * COUT + co) * NTAPS + t) << 5) + cl] =
        __float2bfloat16(v);
  }
}

// ---- kernel 2.5: x f32 [b][cin][sp] -> xt bf16 [b][cc][sp][cin32] ----
__global__ __launch_bounds__(256)
void k_xt(const float* __restrict__ x, __hip_bfloat16* __restrict__ xt) {
  __shared__ __align__(16) float ts[32][524];   // 67 KB, pad for phase-2 conflicts
  int t = threadIdx.x;
  int blk = blockIdx.x;            // 8 b * 4 cc * 64 spchunks
  int b = blk >> 8, cc = (blk >> 6) & 3, sp0 = (blk & 63) << 9;
  const float* xb = x + (size_t)b * CIN * NSP + (size_t)cc * 32 * NSP + sp0;
#pragma unroll
  for (int i = 0; i < 16; i++) {
    int idx = i * 256 + t;
    int cin = idx >> 7, spq = idx & 127;
    float4 v = *(const float4*)(xb + (size_t)cin * NSP + spq * 4);
    *(float4*)&ts[cin][spq * 4] = v;
  }
  __syncthreads();
  __hip_bfloat16* ob = xt + ((size_t)(b * 4 + cc) * NSP + sp0) * 32;
#pragma unroll
  for (int j = 0; j < 8; j++) {
    int chunk = j * 256 + t;
    int sp_l = chunk >> 2, q = chunk & 3;
    union { bf16x8 v; __hip_bfloat16 h[8]; } u;
#pragma unroll
    for (int k = 0; k < 8; k++) u.h[k] = __float2bfloat16(ts[q * 8 + k][sp_l]);
    *(bf16x8*)(ob + (size_t)sp_l * 32 + q * 8) = u.v;
  }
}

// ---------------- kernel 3: implicit-GEMM conv + bias + lrelu*sqrt(2) ----------------
// 128 thr = 2 waves. Block tile: 128 cout x 128 sp (2z x 2y x 32x).
// Wave w owns couts [w*64, w*64+64) and ALL 128 sp (acc 4mi x 8ni) -> A loaded once
// per tap per wave, zero intra-block duplication. b in HIGH blockIdx bits so the
// 4 co-resident blocks/CU share the same wmod slab (L1/L2 reuse).
__global__ __launch_bounds__(128, 2)
void k_conv(const char* __restrict__ ws,
            const float* __restrict__ bias,
            float* __restrict__ out) {
  __shared__ __align__(16) char xs[LDSROWS * ROWB];   // 33792 B, single buffer

  int tid = threadIdx.x;
  int lane = tid & 63, w = tid >> 6;
  int l15 = lane & 15, g = lane >> 4;
  int blk = blockIdx.x;
  int b = blk >> 8;                // batch in high bits: co-resident blocks share b
  int tile = blk & 255;            // 16 tz * 16 ty
  int z0 = (tile >> 4) * 2, y0 = (tile & 15) * 2;

  // zero column init: 16 rows x 64 B at row byte offset 2048 (never re-written)
  {
    int r16 = tid >> 3, c8 = (tid & 7) * 8;
    *(int2*)&xs[r16 * ROWB + 2048 + c8] = make_int2(0, 0);
  }

  // staging lane offset: slot p=tid -> global (hx, q) pre-swizzled (rule #21)
  int hxs = tid >> 2;
  int qs = (tid & 3) ^ ((hxs >> 1) & 3);
  int svoff = (hxs * 4 + qs) * 16;           // byte offset within a (zz,yy) x-row

  // ---- fragment LDS addrs: vaddr[ni][tx], OOB x -> zero column (hx=32) ----
  int vaddr[8][3];
#pragma unroll
  for (int ni = 0; ni < 8; ni++) {
    int row = (ni >> 2) * 4 + ((ni >> 1) & 1);   // dz*4 + dy
    int dx = (ni & 1) * 16 + l15;
#pragma unroll
    for (int tx = 0; tx < 3; tx++) {
      int hx = dx + tx - 1;
      int hxc = ((unsigned)hx > 31u) ? 32 : hx;
      int pos = g ^ ((hxc >> 1) & 3);
      vaddr[ni][tx] = row * ROWB + hxc * 64 + pos * 16;
    }
  }

  // ---- A chunk bases: chunk idx = ((b*4+cc)*128 + cout)*108 + tap*4 + g ----
  const bf16x8* ap = (const bf16x8*)(ws + WM_OFF);
  int abase[4];
#pragma unroll
  for (int mi = 0; mi < 4; mi++)
    abase[mi] = (w * 64 + mi * 16 + l15) * 108 + g;

  f32x4 acc[4][8];
#pragma unroll
  for (int mi = 0; mi < 4; mi++)
#pragma unroll
    for (int ni = 0; ni < 8; ni++) acc[mi][ni] = (f32x4){0.f, 0.f, 0.f, 0.f};

  const char* zpg = ws + ZP_OFF;
  const char* xtb = ws + XT_OFF + (size_t)b * (4 * NSP * 64);

#pragma unroll 1
  for (int cc = 0; cc < 4; cc++) {
    const char* xtc = xtb + (size_t)cc * (NSP * 64);
    int sab = ((b * 4 + cc) * 128) * 108;
    int abc0 = sab + abase[0], abc1 = sab + abase[1];
    int abc2 = sab + abase[2], abc3 = sab + abase[3];

    bf16x8 A[2][4], B0[4], B1[4];
    // A(tap0) issued BEFORE staging; the barrier drains it into regs for free
    A[0][0] = ap[abc0]; A[0][1] = ap[abc1]; A[0][2] = ap[abc2]; A[0][3] = ap[abc3];
    __builtin_amdgcn_sched_barrier(0);

    // stage this cc's halo (16 wave-instrs; row i uniform, lanes = one 1 KB half)
#pragma unroll
    for (int i = 0; i < 16; i++) {
      int zz = z0 + (i >> 2) - 1, yy = y0 + (i & 3) - 1;
      bool ok = ((unsigned)zz < NRES) & ((unsigned)yy < NRES);
      const char* base = ok ? (xtc + (long)((zz << 10) + (yy << 5)) * 64) : zpg;
      __builtin_amdgcn_global_load_lds((gu32*)(base + svoff),
                                       (lu32*)(xs + i * ROWB + w * 1024), 16, 0, 0);
    }
    __syncthreads();   // drains staging + A(tap0); LDS buffer ready

    // B(tap0, ni0-3)
#pragma unroll
    for (int j = 0; j < 4; j++) B0[j] = *(const bf16x8*)(xs + vaddr[j][0]);

#pragma unroll
    for (int t = 0; t < NTAPS; t++) {
      const int tz = t / 9, ty2 = (t / 3) % 3, txx = t % 3;
      const int lit = (tz * 4 + ty2) * ROWB;
      const int s = t & 1;
      // h0 prefetch: B(t, ni4-7)
#pragma unroll
      for (int j = 0; j < 4; j++)
        B1[j] = *(const bf16x8*)(xs + vaddr[4 + j][txx] + lit);
      __builtin_amdgcn_s_setprio(1);
#pragma unroll
      for (int mi = 0; mi < 4; mi++) {
        acc[mi][0] = __builtin_amdgcn_mfma_f32_16x16x32_bf16(A[s][mi], B0[0], acc[mi][0], 0, 0, 0);
        acc[mi][1] = __builtin_amdgcn_mfma_f32_16x16x32_bf16(A[s][mi], B0[1], acc[mi][1], 0, 0, 0);
        acc[mi][2] = __builtin_amdgcn_mfma_f32_16x16x32_bf16(A[s][mi], B0[2], acc[mi][2], 0, 0, 0);
        acc[mi][3] = __builtin_amdgcn_mfma_f32_16x16x32_bf16(A[s][mi], B0[3], acc[mi][3], 0, 0, 0);
      }
      __builtin_amdgcn_s_setprio(0);
      // h1 prefetch: B(t+1, ni0-3) + A(t+1)
      if (t < NTAPS - 1) {
        const int t1 = t + 1;
        const int tz1 = t1 / 9, ty1 = (t1 / 3) % 3, tx1 = t1 % 3;
        const int lit1 = (tz1 * 4 + ty1) * ROWB;
#pragma unroll
        for (int j = 0; j < 4; j++)
          B0[j] = *(const bf16x8*)(xs + vaddr[j][tx1] + lit1);
        A[s ^ 1][0] = ap[abc0 + t1 * 4];
        A[s ^ 1][1] = ap[abc1 + t1 * 4];
        A[s ^ 1][2] = ap[abc2 + t1 * 4];
        A[s ^ 1][3] = ap[abc3 + t1 * 4];
      }
      __builtin_amdgcn_s_setprio(1);
#pragma unroll
      for (int mi = 0; mi < 4; mi++) {
        acc[mi][4] = __builtin_amdgcn_mfma_f32_16x16x32_bf16(A[s][mi], B1[0], acc[mi][4], 0, 0, 0);
        acc[mi][5] = __builtin_amdgcn_mfma_f32_16x16x32_bf16(A[s][mi], B1[1], acc[mi][5], 0, 0, 0);
        acc[mi][6] = __builtin_amdgcn_mfma_f32_16x16x32_bf16(A[s][mi], B1[2], acc[mi][6], 0, 0, 0);
        acc[mi][7] = __builtin_amdgcn_mfma_f32_16x16x32_bf16(A[s][mi], B1[3], acc[mi][7], 0, 0, 0);
      }
      __builtin_amdgcn_s_setprio(0);
    }
    if (cc < 3) __syncthreads();   // LDS readers done before next cc's staging
  }

  // epilogue: cout = w*64 + mi*16 + g*4 + r ; sp = (z0+dz, y0+dy, dx)
  size_t ob = ((size_t)(b * COUT + w * 64 + g * 4)) * NSP +
              (size_t)z0 * 1024 + (size_t)y0 * 32;
#pragma unroll
  for (int mi = 0; mi < 4; mi++) {
    float4 bsv = *(const float4*)(bias + w * 64 + mi * 16 + g * 4);
    float bs[4] = {bsv.x, bsv.y, bsv.z, bsv.w};
#pragma unroll
    for (int ni = 0; ni < 8; ni++) {
      int spo = (ni >> 2) * 1024 + ((ni >> 1) & 1) * 32 + (ni & 1) * 16 + l15;
#pragma unroll
      for (int r = 0; r < 4; r++) {
        float v = acc[mi][ni][r] + bs[r];
        v = (v >= 0.f ? v : v * 0.2f) * 1.41421356237309515f;
        out[ob + (size_t)(mi * 16 + r) * NSP + spo] = v;
      }
    }
  }
}

extern "C" void kernel_launch(void* const* d_in, const int* in_sizes, int n_in,
                              void* d_out, int out_size, void* d_ws, size_t ws_size,
                              hipStream_t stream) {
  const float* x      = (const float*)d_in[0];
  const float* w      = (const float*)d_in[1];
  const float* weight = (const float*)d_in[2];
  const float* aw     = (const float*)d_in[3];
  const float* ab     = (const float*)d_in[4];
  const float* bias   = (const float*)d_in[5];
  float* out = (float*)d_out;

  float* styles = (float*)d_ws;
  float* zeropad = (float*)((char*)d_ws + ZP_OFF);
  __hip_bfloat16* xt = (__hip_bfloat16*)((char*)d_ws + XT_OFF);
  __hip_bfloat16* wmod = (__hip_bfloat16*)((char*)d_ws + WM_OFF);

  k_styles<<<8, 128, 0, stream>>>(w, aw, ab, styles, zeropad);
  k_wmod<<<8 * 128, 256, 0, stream>>>(weight, styles, wmod);
  k_xt<<<8 * 4 * 64, 256, 0, stream>>>(x, xt);
  k_conv<<<8 * 256, 128, 0, stream>>>((const char*)d_ws, bias, out);
}

// Round 7
// 239.812 us; speedup vs baseline: 3.5303x; 1.1916x over previous
//
#include <hip/hip_runtime.h>
#include <hip/hip_bf16.h>

typedef __attribute__((ext_vector_type(8))) short bf16x8;   // 8 bf16 = 4 VGPRs
typedef __attribute__((ext_vector_type(4))) float f32x4;

#define WDIM 512
#define CIN 128
#define COUT 128
#define NRES 32
#define NSP 32768          // 32^3
#define NTAPS 27

#define ROWB 2112          // LDS bytes per (z,y) halo row: 32 hx * 64 B + 64 B zero col
#define LDSROWS 16         // 4 hz * 4 hy

// ws layout (bytes):
//   [0,4096)        styles f32[8][128]
//   [4096,8192)     zeropad (zeroed by k_styles)
//   [8192,+64 MiB)  xt bf16 [8][4cc][32768 sp][32 cin]
//   [+64MiB, +6.75MiB) wmod bf16 [8][4cc][128 cout][27 tap][32 cin]
#define ZP_OFF 4096
#define XT_OFF 8192
#define WM_OFF (8192 + 67108864)

typedef __attribute__((address_space(1))) const unsigned int gu32;
typedef __attribute__((address_space(3))) unsigned int lu32;

// ---------------- kernel 1: styles + zero the pad region ----------------
__global__ void k_styles(const float* __restrict__ w,
                         const float* __restrict__ aw,
                         const float* __restrict__ ab,
                         float* __restrict__ styles,
                         float* __restrict__ zeropad) {
  int b = blockIdx.x;      // 8
  int c = threadIdx.x;     // 128
  if (b == 0) {
#pragma unroll
    for (int i = 0; i < 8; i++) zeropad[i * 128 + c] = 0.f;  // 4096 B
  }
  const float4* wr = (const float4*)(w + (size_t)b * WDIM);
  const float4* ar = (const float4*)(aw + (size_t)c * WDIM);
  float s = 0.f;
#pragma unroll 8
  for (int k = 0; k < WDIM / 4; k++) {
    float4 wv = wr[k], av = ar[k];
    s += wv.x * av.x + wv.y * av.y + wv.z * av.z + wv.w * av.w;
  }
  styles[b * CIN + c] = s * 0.04419417382415922f + ab[c];  // 1/sqrt(512)
}

// ---- kernel 2: modulate+demodulate -> bf16 wmod[b][cc][cout][tap][cin32] ----
__global__ void k_wmod(const float* __restrict__ weight,
                       const float* __restrict__ styles,
                       __hip_bfloat16* __restrict__ wmod) {
  int b = blockIdx.x >> 7;
  int co = blockIdx.x & 127;
  __shared__ float st[CIN];
  __shared__ float red[4];
  int tid = threadIdx.x;   // 256
  if (tid < CIN) st[tid] = styles[b * CIN + tid];
  __syncthreads();
  const float* wr = weight + (size_t)co * (CIN * NTAPS);  // [cin][27] for this cout
  float ss = 0.f;
  for (int o = tid; o < CIN * NTAPS; o += 256) {
    float v = wr[o] * st[o / NTAPS];
    ss += v * v;
  }
#pragma unroll
  for (int off = 32; off > 0; off >>= 1) ss += __shfl_down(ss, off);
  if ((tid & 63) == 0) red[tid >> 6] = ss;
  __syncthreads();
  float d = rsqrtf(red[0] + red[1] + red[2] + red[3] + 1e-8f);
  for (int o = tid; o < CIN * NTAPS; o += 256) {
    int t = o >> 7;
    int cin = o & 127;
    float v = wr[cin * NTAPS + t] * st[cin] * d;
    int cc = cin >> 5, cl = cin & 31;
    wmod[((((size_t)(b * 4 + cc) * COUT + co) * NTAPS + t) << 5) + cl] =
        __float2bfloat16(v);
  }
}

// ---- kernel 2.5: x f32 [b][cin][sp] -> xt bf16 [b][cc][sp][cin32] ----
__global__ __launch_bounds__(256)
void k_xt(const float* __restrict__ x, __hip_bfloat16* __restrict__ xt) {
  __shared__ __align__(16) float ts[32][524];   // 67 KB, pad for phase-2 conflicts
  int t = threadIdx.x;
  int blk = blockIdx.x;            // 8 b * 4 cc * 64 spchunks
  int b = blk >> 8, cc = (blk >> 6) & 3, sp0 = (blk & 63) << 9;
  const float* xb = x + (size_t)b * CIN * NSP + (size_t)cc * 32 * NSP + sp0;
#pragma unroll
  for (int i = 0; i < 16; i++) {
    int idx = i * 256 + t;
    int cin = idx >> 7, spq = idx & 127;
    float4 v = *(const float4*)(xb + (size_t)cin * NSP + spq * 4);
    *(float4*)&ts[cin][spq * 4] = v;
  }
  __syncthreads();
  __hip_bfloat16* ob = xt + ((size_t)(b * 4 + cc) * NSP + sp0) * 32;
#pragma unroll
  for (int j = 0; j < 8; j++) {
    int chunk = j * 256 + t;
    int sp_l = chunk >> 2, q = chunk & 3;
    union { bf16x8 v; __hip_bfloat16 h[8]; } u;
#pragma unroll
    for (int k = 0; k < 8; k++) u.h[k] = __float2bfloat16(ts[q * 8 + k][sp_l]);
    *(bf16x8*)(ob + (size_t)sp_l * 32 + q * 8) = u.v;
  }
}

// ---------------- kernel 3: implicit-GEMM conv + bias + lrelu*sqrt(2) ----------------
// 128 thr = 2 waves. Block tile: 128 cout x 128 sp (2z x 2y x 32x).
// Wave w owns couts [w*64, w*64+64) and ALL 128 sp (acc 4mi x 8ni) -> A loaded once
// per tap per wave. b = blk&7: round-robin dispatch pins one batch per XCD, so each
// XCD's L2 holds its batch's wmod (884 KB) and sequential xt tiles -> A/staging L2-hit.
// A(t+1) issued at TOP of tap t (full-tap ~520 cy prefetch distance >= L2 latency).
__global__ __launch_bounds__(128, 2)
void k_conv(const char* __restrict__ ws,
            const float* __restrict__ bias,
            float* __restrict__ out) {
  __shared__ __align__(16) char xs[LDSROWS * ROWB];   // 33792 B, single buffer

  int tid = threadIdx.x;
  int lane = tid & 63, w = tid >> 6;
  int l15 = lane & 15, g = lane >> 4;
  int blk = blockIdx.x;
  int b = blk & 7;                 // one batch per XCD (wmod/xt L2 locality)
  int tile = blk >> 3;             // 16 tz * 16 ty, sequential per XCD
  int z0 = (tile >> 4) * 2, y0 = (tile & 15) * 2;

  // zero column init: 16 rows x 64 B at row byte offset 2048 (never re-written)
  {
    int r16 = tid >> 3, c8 = (tid & 7) * 8;
    *(int2*)&xs[r16 * ROWB + 2048 + c8] = make_int2(0, 0);
  }

  // staging lane offset: slot p=tid -> global (hx, q) pre-swizzled (rule #21)
  int hxs = tid >> 2;
  int qs = (tid & 3) ^ ((hxs >> 1) & 3);
  int svoff = (hxs * 4 + qs) * 16;           // byte offset within a (zz,yy) x-row

  // ---- fragment LDS addrs: vaddr[ni][tx], OOB x -> zero column (hx=32) ----
  int vaddr[8][3];
#pragma unroll
  for (int ni = 0; ni < 8; ni++) {
    int row = (ni >> 2) * 4 + ((ni >> 1) & 1);   // dz*4 + dy
    int dx = (ni & 1) * 16 + l15;
#pragma unroll
    for (int tx = 0; tx < 3; tx++) {
      int hx = dx + tx - 1;
      int hxc = ((unsigned)hx > 31u) ? 32 : hx;
      int pos = g ^ ((hxc >> 1) & 3);
      vaddr[ni][tx] = row * ROWB + hxc * 64 + pos * 16;
    }
  }

  // ---- A chunk bases: chunk idx = ((b*4+cc)*128 + cout)*108 + tap*4 + g ----
  const bf16x8* ap = (const bf16x8*)(ws + WM_OFF);
  int abase[4];
#pragma unroll
  for (int mi = 0; mi < 4; mi++)
    abase[mi] = (w * 64 + mi * 16 + l15) * 108 + g;

  f32x4 acc[4][8];
#pragma unroll
  for (int mi = 0; mi < 4; mi++)
#pragma unroll
    for (int ni = 0; ni < 8; ni++) acc[mi][ni] = (f32x4){0.f, 0.f, 0.f, 0.f};

  const char* zpg = ws + ZP_OFF;
  const char* xtb = ws + XT_OFF + (size_t)b * (4 * NSP * 64);

#pragma unroll 1
  for (int cc = 0; cc < 4; cc++) {
    const char* xtc = xtb + (size_t)cc * (NSP * 64);
    int sab = ((b * 4 + cc) * 128) * 108;
    int abc0 = sab + abase[0], abc1 = sab + abase[1];
    int abc2 = sab + abase[2], abc3 = sab + abase[3];

    bf16x8 A[2][4], B0[4], B1[4];
    // A(tap0) issued BEFORE staging; the barrier drains it into regs for free
    A[0][0] = ap[abc0]; A[0][1] = ap[abc1]; A[0][2] = ap[abc2]; A[0][3] = ap[abc3];
    __builtin_amdgcn_sched_barrier(0);

    // stage this cc's halo (16 wave-instrs; row i uniform, lanes = one 1 KB half)
#pragma unroll
    for (int i = 0; i < 16; i++) {
      int zz = z0 + (i >> 2) - 1, yy = y0 + (i & 3) - 1;
      bool ok = ((unsigned)zz < NRES) & ((unsigned)yy < NRES);
      const char* base = ok ? (xtc + (long)((zz << 10) + (yy << 5)) * 64) : zpg;
      __builtin_amdgcn_global_load_lds((gu32*)(base + svoff),
                                       (lu32*)(xs + i * ROWB + w * 1024), 16, 0, 0);
    }
    __syncthreads();   // drains staging + A(tap0); LDS buffer ready

    // B(tap0, ni0-3)
#pragma unroll
    for (int j = 0; j < 4; j++) B0[j] = *(const bf16x8*)(xs + vaddr[j][0]);

#pragma unroll
    for (int t = 0; t < NTAPS; t++) {
      const int tz = t / 9, ty2 = (t / 3) % 3, txx = t % 3;
      const int lit = (tz * 4 + ty2) * ROWB;
      const int s = t & 1;
      // A(t+1) issued at TOP of tap: full-tap prefetch distance
      if (t < NTAPS - 1) {
        const int t1 = t + 1;
        A[s ^ 1][0] = ap[abc0 + t1 * 4];
        A[s ^ 1][1] = ap[abc1 + t1 * 4];
        A[s ^ 1][2] = ap[abc2 + t1 * 4];
        A[s ^ 1][3] = ap[abc3 + t1 * 4];
      }
      // h0 prefetch: B(t, ni4-7)
#pragma unroll
      for (int j = 0; j < 4; j++)
        B1[j] = *(const bf16x8*)(xs + vaddr[4 + j][txx] + lit);
      __builtin_amdgcn_s_setprio(1);
#pragma unroll
      for (int mi = 0; mi < 4; mi++) {
        acc[mi][0] = __builtin_amdgcn_mfma_f32_16x16x32_bf16(A[s][mi], B0[0], acc[mi][0], 0, 0, 0);
        acc[mi][1] = __builtin_amdgcn_mfma_f32_16x16x32_bf16(A[s][mi], B0[1], acc[mi][1], 0, 0, 0);
        acc[mi][2] = __builtin_amdgcn_mfma_f32_16x16x32_bf16(A[s][mi], B0[2], acc[mi][2], 0, 0, 0);
        acc[mi][3] = __builtin_amdgcn_mfma_f32_16x16x32_bf16(A[s][mi], B0[3], acc[mi][3], 0, 0, 0);
      }
      __builtin_amdgcn_s_setprio(0);
      // h1 prefetch: B(t+1, ni0-3)
      if (t < NTAPS - 1) {
        const int t1 = t + 1;
        const int tz1 = t1 / 9, ty1 = (t1 / 3) % 3, tx1 = t1 % 3;
        const int lit1 = (tz1 * 4 + ty1) * ROWB;
#pragma unroll
        for (int j = 0; j < 4; j++)
          B0[j] = *(const bf16x8*)(xs + vaddr[j][tx1] + lit1);
      }
      __builtin_amdgcn_s_setprio(1);
#pragma unroll
      for (int mi = 0; mi < 4; mi++) {
        acc[mi][4] = __builtin_amdgcn_mfma_f32_16x16x32_bf16(A[s][mi], B1[0], acc[mi][4], 0, 0, 0);
        acc[mi][5] = __builtin_amdgcn_mfma_f32_16x16x32_bf16(A[s][mi], B1[1], acc[mi][5], 0, 0, 0);
        acc[mi][6] = __builtin_amdgcn_mfma_f32_16x16x32_bf16(A[s][mi], B1[2], acc[mi][6], 0, 0, 0);
        acc[mi][7] = __builtin_amdgcn_mfma_f32_16x16x32_bf16(A[s][mi], B1[3], acc[mi][7], 0, 0, 0);
      }
      __builtin_amdgcn_s_setprio(0);
    }
    if (cc < 3) __syncthreads();   // LDS readers done before next cc's staging
  }

  // epilogue: cout = w*64 + mi*16 + g*4 + r ; sp = (z0+dz, y0+dy, dx)
  size_t ob = ((size_t)(b * COUT + w * 64 + g * 4)) * NSP +
              (size_t)z0 * 1024 + (size_t)y0 * 32;
#pragma unroll
  for (int mi = 0; mi < 4; mi++) {
    float4 bsv = *(const float4*)(bias + w * 64 + mi * 16 + g * 4);
    float bs[4] = {bsv.x, bsv.y, bsv.z, bsv.w};
#pragma unroll
    for (int ni = 0; ni < 8; ni++) {
      int spo = (ni >> 2) * 1024 + ((ni >> 1) & 1) * 32 + (ni & 1) * 16 + l15;
#pragma unroll
      for (int r = 0; r < 4; r++) {
        float v = acc[mi][ni][r] + bs[r];
        v = (v >= 0.f ? v : v * 0.2f) * 1.41421356237309515f;
        out[ob + (size_t)(mi * 16 + r) * NSP + spo] = v;
      }
    }
  }
}

extern "C" void kernel_launch(void* const* d_in, const int* in_sizes, int n_in,
                              void* d_out, int out_size, void* d_ws, size_t ws_size,
                              hipStream_t stream) {
  const float* x      = (const float*)d_in[0];
  const float* w      = (const float*)d_in[1];
  const float* weight = (const float*)d_in[2];
  const float* aw     = (const float*)d_in[3];
  const float* ab     = (const float*)d_in[4];
  const float* bias   = (const float*)d_in[5];
  float* out = (float*)d_out;

  float* styles = (float*)d_ws;
  float* zeropad = (float*)((char*)d_ws + ZP_OFF);
  __hip_bfloat16* xt = (__hip_bfloat16*)((char*)d_ws + XT_OFF);
  __hip_bfloat16* wmod = (__hip_bfloat16*)((char*)d_ws + WM_OFF);

  k_styles<<<8, 128, 0, stream>>>(w, aw, ab, styles, zeropad);
  k_wmod<<<8 * 128, 256, 0, stream>>>(weight, styles, wmod);
  k_xt<<<8 * 4 * 64, 256, 0, stream>>>(x, xt);
  k_conv<<<8 * 256, 128, 0, stream>>>((const char*)d_ws, bias, out);
}